// Round 2
// baseline (723.280 us; speedup 1.0000x reference)
//
#include <hip/hip_runtime.h>
#include <hip/hip_bf16.h>

#define D_FEAT 128
#define HIDDEN 16
#define NCLS 40
#define SCAN_T 1024

// ---------------------------------------------------------------------------
// Kernel 1: yl = x @ W_l ; yr = x @ W_r
// ---------------------------------------------------------------------------
__global__ __launch_bounds__(256) void lin_kernel(
    const float* __restrict__ x,
    const float* __restrict__ Wl, const float* __restrict__ Wr,
    float* __restrict__ yl, float* __restrict__ yr, int N) {
  __shared__ float sW[D_FEAT][8][4];
  __shared__ float sx[32][132];

  int tid = threadIdx.x;
  for (int idx = tid; idx < D_FEAT * 32; idx += 256) {
    int k = idx >> 5, o = idx & 31;
    float v = (o < 16) ? Wl[k * 16 + o] : Wr[k * 16 + (o - 16)];
    sW[k][o >> 2][o & 3] = v;
  }

  int row0 = blockIdx.x * 32;
  for (int q = tid; q < 32 * 32; q += 256) {
    int r = q >> 5, k4 = q & 31;
    int row = row0 + r;
    float4 v = make_float4(0.f, 0.f, 0.f, 0.f);
    if (row < N) v = *(const float4*)(x + (size_t)row * D_FEAT + k4 * 4);
    *(float4*)(&sx[r][k4 * 4]) = v;
  }
  __syncthreads();

  int r = tid >> 3, oq = tid & 7;
  int row = row0 + r;
  if (row < N) {
    float4 acc = make_float4(0.f, 0.f, 0.f, 0.f);
#pragma unroll
    for (int k = 0; k < D_FEAT; ++k) {
      float xv = sx[r][k];
      const float4 w = *(const float4*)(&sW[k][oq][0]);
      acc.x += xv * w.x; acc.y += xv * w.y;
      acc.z += xv * w.z; acc.w += xv * w.w;
    }
    if (oq < 4)
      *(float4*)(yl + (size_t)row * 16 + oq * 4) = acc;
    else
      *(float4*)(yr + (size_t)row * 16 + (oq - 4) * 4) = acc;
  }
}

// ---------------------------------------------------------------------------
// zero ints
// ---------------------------------------------------------------------------
__global__ __launch_bounds__(256) void zero_kernel(int4* __restrict__ p, int nvec) {
  int i = blockIdx.x * 256 + threadIdx.x;
  if (i < nvec) p[i] = make_int4(0, 0, 0, 0);
}

// ---------------------------------------------------------------------------
// Histogram of dst -> count[N]
// ---------------------------------------------------------------------------
__global__ __launch_bounds__(256) void hist_kernel(
    const int* __restrict__ dst, int* __restrict__ count, int E) {
  int i = blockIdx.x * 256 + threadIdx.x;
  int E4 = E >> 2;
  if (i < E4) {
    int4 d = ((const int4*)dst)[i];
    atomicAdd(&count[d.x], 1);
    atomicAdd(&count[d.y], 1);
    atomicAdd(&count[d.z], 1);
    atomicAdd(&count[d.w], 1);
  }
  if (i < (E & 3)) atomicAdd(&count[E4 * 4 + i >= E ? 0 : dst[E4 * 4 + i]], 1);
}

// ---------------------------------------------------------------------------
// Single-block exclusive scan of count[N] -> offsets[N], cursor[N]
// ---------------------------------------------------------------------------
__global__ __launch_bounds__(SCAN_T) void scan_kernel(
    const int* __restrict__ count, int* __restrict__ offsets,
    int* __restrict__ cursor, int N) {
  __shared__ int ssum[SCAN_T];
  int tid = threadIdx.x;
  int chunk = (N + SCAN_T - 1) / SCAN_T;
  int lo = tid * chunk, hi = min(lo + chunk, N);
  int s = 0;
  for (int i = lo; i < hi; ++i) s += count[i];
  ssum[tid] = s;
  __syncthreads();
  for (int d = 1; d < SCAN_T; d <<= 1) {
    int t = 0;
    if (tid >= d) t = ssum[tid - d];
    __syncthreads();
    if (tid >= d) ssum[tid] += t;
    __syncthreads();
  }
  int run = ssum[tid] - s;   // exclusive prefix of this chunk
  for (int i = lo; i < hi; ++i) {
    int c = count[i];
    offsets[i] = run;
    cursor[i] = run;
    run += c;
  }
}

// ---------------------------------------------------------------------------
// Reorder: counting-sort src ids by dst
// ---------------------------------------------------------------------------
__global__ __launch_bounds__(256) void reorder_kernel(
    const int* __restrict__ src, const int* __restrict__ dst,
    int* __restrict__ cursor, int* __restrict__ sorted_src, int E) {
  int i = blockIdx.x * 256 + threadIdx.x;
  int E4 = E >> 2;
  if (i < E4) {
    int4 s = ((const int4*)src)[i];
    int4 d = ((const int4*)dst)[i];
    int p0 = atomicAdd(&cursor[d.x], 1); sorted_src[p0] = s.x;
    int p1 = atomicAdd(&cursor[d.y], 1); sorted_src[p1] = s.y;
    int p2 = atomicAdd(&cursor[d.z], 1); sorted_src[p2] = s.z;
    int p3 = atomicAdd(&cursor[d.w], 1); sorted_src[p3] = s.w;
  }
  if (i < (E & 3)) {
    int e = E4 * 4 + i;
    int p = atomicAdd(&cursor[dst[e]], 1);
    sorted_src[p] = src[e];
  }
}

// ---------------------------------------------------------------------------
// Aggregate: 16 lanes per node, no atomics. agg[n][f] = sum yl[src][f]
// ---------------------------------------------------------------------------
__global__ __launch_bounds__(256) void aggregate_kernel(
    const float* __restrict__ yl, const int* __restrict__ sorted_src,
    const int* __restrict__ offsets, const int* __restrict__ cursor,
    float* __restrict__ agg, int N) {
  int gid = blockIdx.x * 256 + threadIdx.x;
  int n = gid >> 4;
  if (n >= N) return;
  int f = gid & 15;
  int j = offsets[n];
  int end = cursor[n];   // == offsets[n] + count[n] after reorder
  float acc = 0.f;
  for (; j + 1 < end; j += 2) {
    int s0 = sorted_src[j], s1 = sorted_src[j + 1];
    acc += yl[(size_t)s0 * 16 + f] + yl[(size_t)s1 * 16 + f];
  }
  if (j < end) acc += yl[(size_t)sorted_src[j] * 16 + f];
  agg[(size_t)n * 16 + f] = acc;
}

// ---------------------------------------------------------------------------
// Finish: mean, +b_l+yr, relu, @W3+b3, log_softmax
// ---------------------------------------------------------------------------
__global__ __launch_bounds__(256) void finish_kernel(
    const float* __restrict__ agg, const int* __restrict__ count,
    const float* __restrict__ yr, const float* __restrict__ bl,
    const float* __restrict__ W3, const float* __restrict__ b3,
    float* __restrict__ out, int N) {
  __shared__ float sW3[16 * NCLS];
  __shared__ float sb3[NCLS];
  __shared__ float sbl[16];
  __shared__ float slog[256][NCLS + 1];

  int tid = threadIdx.x;
  for (int idx = tid; idx < 16 * NCLS; idx += 256) sW3[idx] = W3[idx];
  if (tid < NCLS) sb3[tid] = b3[tid];
  if (tid < 16) sbl[tid] = bl[tid];
  __syncthreads();

  int row0 = blockIdx.x * 256;
  int n = row0 + tid;
  if (n < N) {
    float inv = 1.0f / fmaxf((float)count[n], 1.0f);
    float h[16];
#pragma unroll
    for (int k = 0; k < 16; ++k)
      h[k] = fmaxf(agg[(size_t)n * 16 + k] * inv + sbl[k] + yr[(size_t)n * 16 + k], 0.0f);

    float lg[NCLS];
#pragma unroll
    for (int c = 0; c < NCLS; ++c) lg[c] = sb3[c];
#pragma unroll
    for (int k = 0; k < 16; ++k) {
      float hv = h[k];
#pragma unroll
      for (int c = 0; c < NCLS; ++c) lg[c] += hv * sW3[k * NCLS + c];
    }

    float m = lg[0];
#pragma unroll
    for (int c = 1; c < NCLS; ++c) m = fmaxf(m, lg[c]);
    float ssum = 0.f;
#pragma unroll
    for (int c = 0; c < NCLS; ++c) ssum += __expf(lg[c] - m);
    float lse = m + __logf(ssum);
#pragma unroll
    for (int c = 0; c < NCLS; ++c) slog[tid][c] = lg[c] - lse;
  }
  __syncthreads();

  int cnt = min(256, N - row0);
  int total = cnt * NCLS;
  for (int idx = tid; idx < total; idx += 256) {
    int r = idx / NCLS, c = idx - r * NCLS;
    out[(size_t)row0 * NCLS + idx] = slog[r][c];
  }
}

// ---------------------------------------------------------------------------
extern "C" void kernel_launch(void* const* d_in, const int* in_sizes, int n_in,
                              void* d_out, int out_size, void* d_ws, size_t ws_size,
                              hipStream_t stream) {
  const float* x   = (const float*)d_in[0];
  const int* eidx  = (const int*)d_in[1];
  const float* Wl  = (const float*)d_in[2];
  const float* bl  = (const float*)d_in[3];
  const float* Wr  = (const float*)d_in[4];
  const float* W3  = (const float*)d_in[5];
  const float* b3  = (const float*)d_in[6];
  float* out = (float*)d_out;

  int N = in_sizes[0] / D_FEAT;
  int E = in_sizes[1] / 2;
  const int* src = eidx;
  const int* dst = eidx + E;

  // workspace layout
  size_t n16 = (size_t)N * 16;
  float* yl  = (float*)d_ws;                 // N*16 f
  float* yr  = yl + n16;                     // N*16 f
  float* agg = yr + n16;                     // N*16 f
  int* count   = (int*)(agg + n16);          // N int
  int* offsets = count + N;                  // N int
  int* cursor  = offsets + N;                // N int
  int* sorted_src = cursor + N;              // E int

  // 1) zero count
  int nvec = (N + 3) / 4;
  zero_kernel<<<(nvec + 255) / 256, 256, 0, stream>>>((int4*)count, nvec);

  // 2) histogram of dst
  int E4 = E >> 2;
  int nbh = (max(E4, 1) + 255) / 256;
  hist_kernel<<<nbh, 256, 0, stream>>>(dst, count, E);

  // 3) exclusive scan -> offsets, cursor
  scan_kernel<<<1, SCAN_T, 0, stream>>>(count, offsets, cursor, N);

  // 4) projections (needed before aggregate)
  int nb1 = (N + 31) / 32;
  lin_kernel<<<nb1, 256, 0, stream>>>(x, Wl, Wr, yl, yr, N);

  // 5) reorder: counting sort src by dst
  reorder_kernel<<<nbh, 256, 0, stream>>>(src, dst, cursor, sorted_src, E);

  // 6) aggregate (no atomics)
  int nb6 = (N * 16 + 255) / 256;
  aggregate_kernel<<<nb6, 256, 0, stream>>>(yl, sorted_src, offsets, cursor, agg, N);

  // 7) finish
  int nb7 = (N + 255) / 256;
  finish_kernel<<<nb7, 256, 0, stream>>>(agg, count, yr, bl, W3, b3, out, N);
}

// Round 3
// 463.744 us; speedup vs baseline: 1.5597x; 1.5597x over previous
//
#include <hip/hip_runtime.h>
#include <hip/hip_bf16.h>

#define D_FEAT 128
#define HIDDEN 16
#define NCLS 40
#define NODES_PER_BUCKET 128      // bucket = dst >> 7
#define MAXB 1024                 // max buckets supported (N <= 131072)
#define EPB 16384                 // edges per block in hist/place

// ---------------------------------------------------------------------------
// Kernel: yl = x @ W_l ; yr = x @ W_r
// ---------------------------------------------------------------------------
__global__ __launch_bounds__(256) void lin_kernel(
    const float* __restrict__ x,
    const float* __restrict__ Wl, const float* __restrict__ Wr,
    float* __restrict__ yl, float* __restrict__ yr, int N) {
  __shared__ float sW[D_FEAT][8][4];
  __shared__ float sx[32][132];

  int tid = threadIdx.x;
  for (int idx = tid; idx < D_FEAT * 32; idx += 256) {
    int k = idx >> 5, o = idx & 31;
    float v = (o < 16) ? Wl[k * 16 + o] : Wr[k * 16 + (o - 16)];
    sW[k][o >> 2][o & 3] = v;
  }

  int row0 = blockIdx.x * 32;
  for (int q = tid; q < 32 * 32; q += 256) {
    int r = q >> 5, k4 = q & 31;
    int row = row0 + r;
    float4 v = make_float4(0.f, 0.f, 0.f, 0.f);
    if (row < N) v = *(const float4*)(x + (size_t)row * D_FEAT + k4 * 4);
    *(float4*)(&sx[r][k4 * 4]) = v;
  }
  __syncthreads();

  int r = tid >> 3, oq = tid & 7;
  int row = row0 + r;
  if (row < N) {
    float4 acc = make_float4(0.f, 0.f, 0.f, 0.f);
#pragma unroll
    for (int k = 0; k < D_FEAT; ++k) {
      float xv = sx[r][k];
      const float4 w = *(const float4*)(&sW[k][oq][0]);
      acc.x += xv * w.x; acc.y += xv * w.y;
      acc.z += xv * w.z; acc.w += xv * w.w;
    }
    if (oq < 4)
      *(float4*)(yl + (size_t)row * 16 + oq * 4) = acc;
    else
      *(float4*)(yr + (size_t)row * 16 + (oq - 4) * 4) = acc;
  }
}

// ---------------------------------------------------------------------------
// zero ints (bucket counters)
// ---------------------------------------------------------------------------
__global__ __launch_bounds__(256) void zero_kernel(int* __restrict__ p, int n) {
  int i = blockIdx.x * 256 + threadIdx.x;
  if (i < n) p[i] = 0;
}

// ---------------------------------------------------------------------------
// Per-block LDS histogram of dst buckets -> global bcount
// ---------------------------------------------------------------------------
__global__ __launch_bounds__(256) void bhist_kernel(
    const int* __restrict__ dst, int* __restrict__ bcount, int E, int B) {
  __shared__ int lh[MAXB];
  int tid = threadIdx.x;
  for (int i = tid; i < B; i += 256) lh[i] = 0;
  __syncthreads();
  int base = blockIdx.x * EPB;
  int end = min(base + EPB, E);
  for (int e = base + tid; e < end; e += 256)
    atomicAdd(&lh[dst[e] >> 7], 1);
  __syncthreads();
  for (int i = tid; i < B; i += 256) {
    int c = lh[i];
    if (c) atomicAdd(&bcount[i], c);
  }
}

// ---------------------------------------------------------------------------
// Single-block scan over B (<=1024) buckets -> boff[B+1], gcur[B]
// ---------------------------------------------------------------------------
__global__ __launch_bounds__(1024) void bscan_kernel(
    const int* __restrict__ bcount, int* __restrict__ boff,
    int* __restrict__ gcur, int B) {
  __shared__ int s[1024];
  int tid = threadIdx.x;
  int v = (tid < B) ? bcount[tid] : 0;
  s[tid] = v;
  __syncthreads();
  for (int d = 1; d < 1024; d <<= 1) {
    int t = (tid >= d) ? s[tid - d] : 0;
    __syncthreads();
    if (tid >= d) s[tid] += t;
    __syncthreads();
  }
  if (tid < B) {
    int off = s[tid] - v;     // exclusive prefix
    boff[tid] = off;
    gcur[tid] = off;
  }
  if (tid == B - 1) boff[B] = s[tid];
}

// ---------------------------------------------------------------------------
// Place: block-level counting sort of edges into bucket-contiguous storage.
// packed = src | (local_dst << 20)
// ---------------------------------------------------------------------------
__global__ __launch_bounds__(256) void place_kernel(
    const int* __restrict__ src, const int* __restrict__ dst,
    int* __restrict__ gcur, int* __restrict__ packed, int E, int B) {
  __shared__ int lh[MAXB];
  __shared__ int lbase[MAXB];
  int tid = threadIdx.x;
  for (int i = tid; i < B; i += 256) lh[i] = 0;
  __syncthreads();
  int base = blockIdx.x * EPB;
  int end = min(base + EPB, E);
  for (int e = base + tid; e < end; e += 256)
    atomicAdd(&lh[dst[e] >> 7], 1);
  __syncthreads();
  for (int i = tid; i < B; i += 256) {
    int c = lh[i];
    lbase[i] = c ? atomicAdd(&gcur[i], c) : 0;
    lh[i] = 0;
  }
  __syncthreads();
  for (int e = base + tid; e < end; e += 256) {
    int d = dst[e], s = src[e];
    int b = d >> 7;
    int p = atomicAdd(&lh[b], 1);
    packed[lbase[b] + p] = s | ((d & 127) << 20);
  }
}

// ---------------------------------------------------------------------------
// Bucket aggregate: one block per bucket, LDS accumulation, no global atomics
// ---------------------------------------------------------------------------
__global__ __launch_bounds__(256) void baggr_kernel(
    const float* __restrict__ yl, const int* __restrict__ packed,
    const int* __restrict__ boff, float* __restrict__ agg,
    int* __restrict__ count, int N) {
  __shared__ float sagg[NODES_PER_BUCKET * 16];   // 8KB
  __shared__ int sdeg[NODES_PER_BUCKET];
  int tid = threadIdx.x;
  int b = blockIdx.x;
  for (int i = tid; i < NODES_PER_BUCKET * 16; i += 256) sagg[i] = 0.f;
  if (tid < NODES_PER_BUCKET) sdeg[tid] = 0;
  __syncthreads();

  int lo = boff[b], hi = boff[b + 1];
  int g = tid >> 4, f = tid & 15;   // 16 groups x 16 feature lanes
  for (int j = lo + g; j < hi; j += 16) {
    int p = packed[j];
    int s = p & 0xFFFFF;
    int ld = p >> 20;
    float v = yl[(size_t)s * 16 + f];
    atomicAdd(&sagg[ld * 16 + f], v);
    if (f == 0) atomicAdd(&sdeg[ld], 1);
  }
  __syncthreads();

  int node0 = b * NODES_PER_BUCKET;
  for (int i = tid; i < NODES_PER_BUCKET * 16; i += 256) {
    int node = node0 + (i >> 4);
    if (node < N) agg[(size_t)node0 * 16 + i] = sagg[i];
  }
  if (tid < NODES_PER_BUCKET && node0 + tid < N) count[node0 + tid] = sdeg[tid];
}

// ---------------------------------------------------------------------------
// Finish: mean, +b_l+yr, relu, @W3+b3, log_softmax
// ---------------------------------------------------------------------------
__global__ __launch_bounds__(256) void finish_kernel(
    const float* __restrict__ agg, const int* __restrict__ count,
    const float* __restrict__ yr, const float* __restrict__ bl,
    const float* __restrict__ W3, const float* __restrict__ b3,
    float* __restrict__ out, int N) {
  __shared__ float sW3[16 * NCLS];
  __shared__ float sb3[NCLS];
  __shared__ float sbl[16];
  __shared__ float slog[256][NCLS + 1];

  int tid = threadIdx.x;
  for (int idx = tid; idx < 16 * NCLS; idx += 256) sW3[idx] = W3[idx];
  if (tid < NCLS) sb3[tid] = b3[tid];
  if (tid < 16) sbl[tid] = bl[tid];
  __syncthreads();

  int row0 = blockIdx.x * 256;
  int n = row0 + tid;
  if (n < N) {
    float inv = 1.0f / fmaxf((float)count[n], 1.0f);
    float h[16];
#pragma unroll
    for (int k = 0; k < 16; ++k)
      h[k] = fmaxf(agg[(size_t)n * 16 + k] * inv + sbl[k] + yr[(size_t)n * 16 + k], 0.0f);

    float lg[NCLS];
#pragma unroll
    for (int c = 0; c < NCLS; ++c) lg[c] = sb3[c];
#pragma unroll
    for (int k = 0; k < 16; ++k) {
      float hv = h[k];
#pragma unroll
      for (int c = 0; c < NCLS; ++c) lg[c] += hv * sW3[k * NCLS + c];
    }

    float m = lg[0];
#pragma unroll
    for (int c = 1; c < NCLS; ++c) m = fmaxf(m, lg[c]);
    float ssum = 0.f;
#pragma unroll
    for (int c = 0; c < NCLS; ++c) ssum += __expf(lg[c] - m);
    float lse = m + __logf(ssum);
#pragma unroll
    for (int c = 0; c < NCLS; ++c) slog[tid][c] = lg[c] - lse;
  }
  __syncthreads();

  int cnt = min(256, N - row0);
  int total = cnt * NCLS;
  for (int idx = tid; idx < total; idx += 256) {
    int r = idx / NCLS, c = idx - r * NCLS;
    out[(size_t)row0 * NCLS + idx] = slog[r][c];
  }
}

// ---------------------------------------------------------------------------
extern "C" void kernel_launch(void* const* d_in, const int* in_sizes, int n_in,
                              void* d_out, int out_size, void* d_ws, size_t ws_size,
                              hipStream_t stream) {
  const float* x   = (const float*)d_in[0];
  const int* eidx  = (const int*)d_in[1];
  const float* Wl  = (const float*)d_in[2];
  const float* bl  = (const float*)d_in[3];
  const float* Wr  = (const float*)d_in[4];
  const float* W3  = (const float*)d_in[5];
  const float* b3  = (const float*)d_in[6];
  float* out = (float*)d_out;

  int N = in_sizes[0] / D_FEAT;
  int E = in_sizes[1] / 2;
  const int* src = eidx;
  const int* dst = eidx + E;
  int B = (N + NODES_PER_BUCKET - 1) / NODES_PER_BUCKET;   // 782 for N=100000

  // workspace layout
  size_t n16 = (size_t)N * 16;
  float* yl  = (float*)d_ws;                 // N*16 f
  float* yr  = yl + n16;                     // N*16 f
  float* agg = yr + n16;                     // N*16 f
  int* count  = (int*)(agg + n16);           // N
  int* bcount = count + N;                   // B
  int* boff   = bcount + B;                  // B+1
  int* gcur   = boff + B + 1;                // B
  int* packed = gcur + B;                    // E

  // 1) zero bucket counters
  zero_kernel<<<(B + 255) / 256, 256, 0, stream>>>(bcount, B);

  // 2) bucket histogram
  int nbe = (E + EPB - 1) / EPB;
  bhist_kernel<<<nbe, 256, 0, stream>>>(dst, bcount, E, B);

  // 3) scan -> boff, gcur
  bscan_kernel<<<1, 1024, 0, stream>>>(bcount, boff, gcur, B);

  // 4) place edges into buckets
  place_kernel<<<nbe, 256, 0, stream>>>(src, dst, gcur, packed, E, B);

  // 5) projections
  lin_kernel<<<(N + 31) / 32, 256, 0, stream>>>(x, Wl, Wr, yl, yr, N);

  // 6) bucket aggregate (LDS atomics only)
  baggr_kernel<<<B, 256, 0, stream>>>(yl, packed, boff, agg, count, N);

  // 7) finish
  finish_kernel<<<(N + 255) / 256, 256, 0, stream>>>(agg, count, yr, bl, W3, b3, out, N);
}

// Round 4
// 428.507 us; speedup vs baseline: 1.6879x; 1.0822x over previous
//
#include <hip/hip_runtime.h>
#include <hip/hip_bf16.h>

#define D_FEAT 128
#define HIDDEN 16
#define NCLS 40
#define NODES_PER_BUCKET 128      // bucket = dst >> 7
#define MAXB 1024                 // max buckets supported (N <= 131072)
#define EPB 16384                 // edges per block in hist/place

// ---------------------------------------------------------------------------
// Kernel: yl = x @ W_l ; yr = x @ W_r
// ---------------------------------------------------------------------------
__global__ __launch_bounds__(256) void lin_kernel(
    const float* __restrict__ x,
    const float* __restrict__ Wl, const float* __restrict__ Wr,
    float* __restrict__ yl, float* __restrict__ yr, int N) {
  __shared__ float sW[D_FEAT][8][4];
  __shared__ float sx[32][132];

  int tid = threadIdx.x;
  for (int idx = tid; idx < D_FEAT * 32; idx += 256) {
    int k = idx >> 5, o = idx & 31;
    float v = (o < 16) ? Wl[k * 16 + o] : Wr[k * 16 + (o - 16)];
    sW[k][o >> 2][o & 3] = v;
  }

  int row0 = blockIdx.x * 32;
  for (int q = tid; q < 32 * 32; q += 256) {
    int r = q >> 5, k4 = q & 31;
    int row = row0 + r;
    float4 v = make_float4(0.f, 0.f, 0.f, 0.f);
    if (row < N) v = *(const float4*)(x + (size_t)row * D_FEAT + k4 * 4);
    *(float4*)(&sx[r][k4 * 4]) = v;
  }
  __syncthreads();

  int r = tid >> 3, oq = tid & 7;
  int row = row0 + r;
  if (row < N) {
    float4 acc = make_float4(0.f, 0.f, 0.f, 0.f);
#pragma unroll
    for (int k = 0; k < D_FEAT; ++k) {
      float xv = sx[r][k];
      const float4 w = *(const float4*)(&sW[k][oq][0]);
      acc.x += xv * w.x; acc.y += xv * w.y;
      acc.z += xv * w.z; acc.w += xv * w.w;
    }
    if (oq < 4)
      *(float4*)(yl + (size_t)row * 16 + oq * 4) = acc;
    else
      *(float4*)(yr + (size_t)row * 16 + (oq - 4) * 4) = acc;
  }
}

// ---------------------------------------------------------------------------
// Per-block LDS histogram of dst buckets -> global bcount
// ---------------------------------------------------------------------------
__global__ __launch_bounds__(1024) void bhist_kernel(
    const int* __restrict__ dst, int* __restrict__ bcount, int E, int B) {
  __shared__ int lh[MAXB];
  int tid = threadIdx.x;
  for (int i = tid; i < B; i += 1024) lh[i] = 0;
  __syncthreads();
  int base = blockIdx.x * EPB;
  int end = min(base + EPB, E);
  for (int e = base + tid; e < end; e += 1024)
    atomicAdd(&lh[dst[e] >> 7], 1);
  __syncthreads();
  for (int i = tid; i < B; i += 1024) {
    int c = lh[i];
    if (c) atomicAdd(&bcount[i], c);
  }
}

// ---------------------------------------------------------------------------
// Single-block scan over B (<=1024) buckets -> boff[B+1], gcur[B]
// ---------------------------------------------------------------------------
__global__ __launch_bounds__(1024) void bscan_kernel(
    const int* __restrict__ bcount, int* __restrict__ boff,
    int* __restrict__ gcur, int B) {
  __shared__ int s[1024];
  int tid = threadIdx.x;
  int v = (tid < B) ? bcount[tid] : 0;
  s[tid] = v;
  __syncthreads();
  for (int d = 1; d < 1024; d <<= 1) {
    int t = (tid >= d) ? s[tid - d] : 0;
    __syncthreads();
    if (tid >= d) s[tid] += t;
    __syncthreads();
  }
  if (tid < B) {
    int off = s[tid] - v;     // exclusive prefix
    boff[tid] = off;
    gcur[tid] = off;
  }
  if (tid == B - 1) boff[B] = s[tid];
}

// ---------------------------------------------------------------------------
// Place: block-level counting sort of edges into bucket-contiguous storage.
// packed = src | (local_dst << 20)
// ---------------------------------------------------------------------------
__global__ __launch_bounds__(1024) void place_kernel(
    const int* __restrict__ src, const int* __restrict__ dst,
    int* __restrict__ gcur, int* __restrict__ packed, int E, int B) {
  __shared__ int lh[MAXB];
  __shared__ int lbase[MAXB];
  int tid = threadIdx.x;
  for (int i = tid; i < B; i += 1024) lh[i] = 0;
  __syncthreads();
  int base = blockIdx.x * EPB;
  int end = min(base + EPB, E);
  for (int e = base + tid; e < end; e += 1024)
    atomicAdd(&lh[dst[e] >> 7], 1);
  __syncthreads();
  for (int i = tid; i < B; i += 1024) {
    int c = lh[i];
    lbase[i] = c ? atomicAdd(&gcur[i], c) : 0;
    lh[i] = 0;
  }
  __syncthreads();
  for (int e = base + tid; e < end; e += 1024) {
    int d = dst[e], s = src[e];
    int b = d >> 7;
    int p = atomicAdd(&lh[b], 1);
    packed[lbase[b] + p] = s | ((d & 127) << 20);
  }
}

// ---------------------------------------------------------------------------
// Bucket aggregate: one block per bucket, 1024 threads, 4-edge ILP batches,
// LDS accumulation, no global atomics.
// ---------------------------------------------------------------------------
__global__ __launch_bounds__(1024) void baggr_kernel(
    const float* __restrict__ yl, const int* __restrict__ packed,
    const int* __restrict__ boff, float* __restrict__ agg,
    int* __restrict__ count, int N) {
  __shared__ float sagg[NODES_PER_BUCKET * 16];   // 8KB
  __shared__ int sdeg[NODES_PER_BUCKET];
  int tid = threadIdx.x;
  int b = blockIdx.x;
  for (int i = tid; i < NODES_PER_BUCKET * 16; i += 1024) sagg[i] = 0.f;
  if (tid < NODES_PER_BUCKET) sdeg[tid] = 0;
  __syncthreads();

  int lo = boff[b], hi = boff[b + 1];
  int g = tid >> 4, f = tid & 15;   // 64 groups x 16 feature lanes
  for (int j0 = lo + (g << 2); j0 < hi; j0 += 256) {
    // 4 independent edges per iteration (MLP=4)
    int p0 = packed[j0];
    int p1 = (j0 + 1 < hi) ? packed[j0 + 1] : -1;
    int p2 = (j0 + 2 < hi) ? packed[j0 + 2] : -1;
    int p3 = (j0 + 3 < hi) ? packed[j0 + 3] : -1;
    float v0 = yl[(size_t)(p0 & 0xFFFFF) * 16 + f];
    float v1 = (p1 >= 0) ? yl[(size_t)(p1 & 0xFFFFF) * 16 + f] : 0.f;
    float v2 = (p2 >= 0) ? yl[(size_t)(p2 & 0xFFFFF) * 16 + f] : 0.f;
    float v3 = (p3 >= 0) ? yl[(size_t)(p3 & 0xFFFFF) * 16 + f] : 0.f;
    atomicAdd(&sagg[(p0 >> 20) * 16 + f], v0);
    if (p1 >= 0) atomicAdd(&sagg[(p1 >> 20) * 16 + f], v1);
    if (p2 >= 0) atomicAdd(&sagg[(p2 >> 20) * 16 + f], v2);
    if (p3 >= 0) atomicAdd(&sagg[(p3 >> 20) * 16 + f], v3);
    if (f == 0) {
      atomicAdd(&sdeg[p0 >> 20], 1);
      if (p1 >= 0) atomicAdd(&sdeg[p1 >> 20], 1);
      if (p2 >= 0) atomicAdd(&sdeg[p2 >> 20], 1);
      if (p3 >= 0) atomicAdd(&sdeg[p3 >> 20], 1);
    }
  }
  __syncthreads();

  int node0 = b * NODES_PER_BUCKET;
  for (int i = tid; i < NODES_PER_BUCKET * 16; i += 1024) {
    int node = node0 + (i >> 4);
    if (node < N) agg[(size_t)node0 * 16 + i] = sagg[i];
  }
  if (tid < NODES_PER_BUCKET && node0 + tid < N) count[node0 + tid] = sdeg[tid];
}

// ---------------------------------------------------------------------------
// Finish: mean, +b_l+yr, relu, @W3+b3, log_softmax
// ---------------------------------------------------------------------------
__global__ __launch_bounds__(256) void finish_kernel(
    const float* __restrict__ agg, const int* __restrict__ count,
    const float* __restrict__ yr, const float* __restrict__ bl,
    const float* __restrict__ W3, const float* __restrict__ b3,
    float* __restrict__ out, int N) {
  __shared__ float sW3[16 * NCLS];
  __shared__ float sb3[NCLS];
  __shared__ float sbl[16];
  __shared__ float slog[256][NCLS + 1];

  int tid = threadIdx.x;
  for (int idx = tid; idx < 16 * NCLS; idx += 256) sW3[idx] = W3[idx];
  if (tid < NCLS) sb3[tid] = b3[tid];
  if (tid < 16) sbl[tid] = bl[tid];
  __syncthreads();

  int row0 = blockIdx.x * 256;
  int n = row0 + tid;
  if (n < N) {
    float inv = 1.0f / fmaxf((float)count[n], 1.0f);
    float h[16];
#pragma unroll
    for (int k = 0; k < 16; ++k)
      h[k] = fmaxf(agg[(size_t)n * 16 + k] * inv + sbl[k] + yr[(size_t)n * 16 + k], 0.0f);

    float lg[NCLS];
#pragma unroll
    for (int c = 0; c < NCLS; ++c) lg[c] = sb3[c];
#pragma unroll
    for (int k = 0; k < 16; ++k) {
      float hv = h[k];
#pragma unroll
      for (int c = 0; c < NCLS; ++c) lg[c] += hv * sW3[k * NCLS + c];
    }

    float m = lg[0];
#pragma unroll
    for (int c = 1; c < NCLS; ++c) m = fmaxf(m, lg[c]);
    float ssum = 0.f;
#pragma unroll
    for (int c = 0; c < NCLS; ++c) ssum += __expf(lg[c] - m);
    float lse = m + __logf(ssum);
#pragma unroll
    for (int c = 0; c < NCLS; ++c) slog[tid][c] = lg[c] - lse;
  }
  __syncthreads();

  int cnt = min(256, N - row0);
  int total = cnt * NCLS;
  for (int idx = tid; idx < total; idx += 256) {
    int r = idx / NCLS, c = idx - r * NCLS;
    out[(size_t)row0 * NCLS + idx] = slog[r][c];
  }
}

// ---------------------------------------------------------------------------
extern "C" void kernel_launch(void* const* d_in, const int* in_sizes, int n_in,
                              void* d_out, int out_size, void* d_ws, size_t ws_size,
                              hipStream_t stream) {
  const float* x   = (const float*)d_in[0];
  const int* eidx  = (const int*)d_in[1];
  const float* Wl  = (const float*)d_in[2];
  const float* bl  = (const float*)d_in[3];
  const float* Wr  = (const float*)d_in[4];
  const float* W3  = (const float*)d_in[5];
  const float* b3  = (const float*)d_in[6];
  float* out = (float*)d_out;

  int N = in_sizes[0] / D_FEAT;
  int E = in_sizes[1] / 2;
  const int* src = eidx;
  const int* dst = eidx + E;
  int B = (N + NODES_PER_BUCKET - 1) / NODES_PER_BUCKET;   // 782 for N=100000

  // workspace layout
  size_t n16 = (size_t)N * 16;
  float* yl  = (float*)d_ws;                 // N*16 f
  float* yr  = yl + n16;                     // N*16 f
  float* agg = yr + n16;                     // N*16 f
  int* count  = (int*)(agg + n16);           // N
  int* bcount = count + N;                   // B
  int* boff   = bcount + B;                  // B+1
  int* gcur   = boff + B + 1;                // B
  int* packed = gcur + B;                    // E

  // 1) zero bucket counters (capture-safe async memset)
  hipMemsetAsync(bcount, 0, (size_t)B * sizeof(int), stream);

  // 2) bucket histogram
  int nbe = (E + EPB - 1) / EPB;
  bhist_kernel<<<nbe, 1024, 0, stream>>>(dst, bcount, E, B);

  // 3) scan -> boff, gcur
  bscan_kernel<<<1, 1024, 0, stream>>>(bcount, boff, gcur, B);

  // 4) place edges into buckets
  place_kernel<<<nbe, 1024, 0, stream>>>(src, dst, gcur, packed, E, B);

  // 5) projections
  lin_kernel<<<(N + 31) / 32, 256, 0, stream>>>(x, Wl, Wr, yl, yr, N);

  // 6) bucket aggregate (LDS atomics only)
  baggr_kernel<<<B, 1024, 0, stream>>>(yl, packed, boff, agg, count, N);

  // 7) finish
  finish_kernel<<<(N + 255) / 256, 256, 0, stream>>>(agg, count, yr, bl, W3, b3, out, N);
}

// Round 5
// 425.836 us; speedup vs baseline: 1.6985x; 1.0063x over previous
//
#include <hip/hip_runtime.h>
#include <hip/hip_bf16.h>

#define D_FEAT 128
#define HIDDEN 16
#define NCLS 40
#define NODES_PER_BUCKET 128      // bucket = dst >> 7
#define MAXB 1024                 // max buckets supported (N <= 131072)
#define EPB 16384                 // edges per block in hist/place

typedef unsigned int uint;

__device__ __forceinline__ uint f2bf(float x) {
  uint u = __float_as_uint(x);
  return (u + 0x7FFFu + ((u >> 16) & 1u)) >> 16;   // RNE
}

// ---------------------------------------------------------------------------
// Kernel: ylb = bf16pack(x @ W_l) ; yr = x @ W_r (f32)
// ---------------------------------------------------------------------------
__global__ __launch_bounds__(256) void lin_kernel(
    const float* __restrict__ x,
    const float* __restrict__ Wl, const float* __restrict__ Wr,
    uint* __restrict__ ylb, float* __restrict__ yr, int N) {
  __shared__ float sW[D_FEAT][8][4];
  __shared__ float sx[32][132];

  int tid = threadIdx.x;
  for (int idx = tid; idx < D_FEAT * 32; idx += 256) {
    int k = idx >> 5, o = idx & 31;
    float v = (o < 16) ? Wl[k * 16 + o] : Wr[k * 16 + (o - 16)];
    sW[k][o >> 2][o & 3] = v;
  }

  int row0 = blockIdx.x * 32;
  for (int q = tid; q < 32 * 32; q += 256) {
    int r = q >> 5, k4 = q & 31;
    int row = row0 + r;
    float4 v = make_float4(0.f, 0.f, 0.f, 0.f);
    if (row < N) v = *(const float4*)(x + (size_t)row * D_FEAT + k4 * 4);
    *(float4*)(&sx[r][k4 * 4]) = v;
  }
  __syncthreads();

  int r = tid >> 3, oq = tid & 7;
  int row = row0 + r;
  if (row < N) {
    float4 acc = make_float4(0.f, 0.f, 0.f, 0.f);
#pragma unroll
    for (int k = 0; k < D_FEAT; ++k) {
      float xv = sx[r][k];
      const float4 w = *(const float4*)(&sW[k][oq][0]);
      acc.x += xv * w.x; acc.y += xv * w.y;
      acc.z += xv * w.z; acc.w += xv * w.w;
    }
    if (oq < 4) {
      // bf16-pack quad -> 2 uints (features oq*4 .. oq*4+3)
      uint2 pk;
      pk.x = f2bf(acc.x) | (f2bf(acc.y) << 16);
      pk.y = f2bf(acc.z) | (f2bf(acc.w) << 16);
      *(uint2*)(ylb + (size_t)row * 8 + oq * 2) = pk;
    } else {
      *(float4*)(yr + (size_t)row * 16 + (oq - 4) * 4) = acc;
    }
  }
}

// ---------------------------------------------------------------------------
// Per-block LDS histogram of dst buckets -> global bcount
// ---------------------------------------------------------------------------
__global__ __launch_bounds__(1024) void bhist_kernel(
    const int* __restrict__ dst, int* __restrict__ bcount, int E, int B) {
  __shared__ int lh[MAXB];
  int tid = threadIdx.x;
  for (int i = tid; i < B; i += 1024) lh[i] = 0;
  __syncthreads();
  int base = blockIdx.x * EPB;
  int end = min(base + EPB, E);
  for (int e = base + tid; e < end; e += 1024)
    atomicAdd(&lh[dst[e] >> 7], 1);
  __syncthreads();
  for (int i = tid; i < B; i += 1024) {
    int c = lh[i];
    if (c) atomicAdd(&bcount[i], c);
  }
}

// ---------------------------------------------------------------------------
// Single-block scan over B (<=1024) buckets -> boff[B+1], gcur[B]
// ---------------------------------------------------------------------------
__global__ __launch_bounds__(1024) void bscan_kernel(
    const int* __restrict__ bcount, int* __restrict__ boff,
    int* __restrict__ gcur, int B) {
  __shared__ int s[1024];
  int tid = threadIdx.x;
  int v = (tid < B) ? bcount[tid] : 0;
  s[tid] = v;
  __syncthreads();
  for (int d = 1; d < 1024; d <<= 1) {
    int t = (tid >= d) ? s[tid - d] : 0;
    __syncthreads();
    if (tid >= d) s[tid] += t;
    __syncthreads();
  }
  if (tid < B) {
    int off = s[tid] - v;     // exclusive prefix
    boff[tid] = off;
    gcur[tid] = off;
  }
  if (tid == B - 1) boff[B] = s[tid];
}

// ---------------------------------------------------------------------------
// Place: block-level counting sort of edges into bucket-contiguous storage.
// packed = src | (local_dst << 20)
// ---------------------------------------------------------------------------
__global__ __launch_bounds__(1024) void place_kernel(
    const int* __restrict__ src, const int* __restrict__ dst,
    int* __restrict__ gcur, int* __restrict__ packed, int E, int B) {
  __shared__ int lh[MAXB];
  __shared__ int lbase[MAXB];
  int tid = threadIdx.x;
  for (int i = tid; i < B; i += 1024) lh[i] = 0;
  __syncthreads();
  int base = blockIdx.x * EPB;
  int end = min(base + EPB, E);
  for (int e = base + tid; e < end; e += 1024)
    atomicAdd(&lh[dst[e] >> 7], 1);
  __syncthreads();
  for (int i = tid; i < B; i += 1024) {
    int c = lh[i];
    lbase[i] = c ? atomicAdd(&gcur[i], c) : 0;
    lh[i] = 0;
  }
  __syncthreads();
  for (int e = base + tid; e < end; e += 1024) {
    int d = dst[e], s = src[e];
    int b = d >> 7;
    int p = atomicAdd(&lh[b], 1);
    packed[lbase[b] + p] = s | ((d & 127) << 20);
  }
}

// ---------------------------------------------------------------------------
// Bucket aggregate: one block per bucket, lane-per-edge, bf16 row gathers
// (one 64B line per lane -> 64 lines in flight per wave), LDS f32 accum.
// ---------------------------------------------------------------------------
#define ADD2(dp, idx, u) do {                                       \
    atomicAdd((dp) + (idx),     __uint_as_float((u) << 16));        \
    atomicAdd((dp) + (idx) + 1, __uint_as_float((u) & 0xFFFF0000u));\
  } while (0)

__global__ __launch_bounds__(1024) void baggr_kernel(
    const uint* __restrict__ ylb, const int* __restrict__ packed,
    const int* __restrict__ boff, float* __restrict__ agg,
    int* __restrict__ count, int N) {
  __shared__ float sagg[NODES_PER_BUCKET * 17];   // stride 17: banks spread
  __shared__ int sdeg[NODES_PER_BUCKET];
  int tid = threadIdx.x;
  int b = blockIdx.x;
  for (int i = tid; i < NODES_PER_BUCKET * 17; i += 1024) sagg[i] = 0.f;
  if (tid < NODES_PER_BUCKET) sdeg[tid] = 0;
  __syncthreads();

  int lo = boff[b], hi = boff[b + 1];
  for (int e = lo + tid; e < hi; e += 2048) {
    int eb = e + 1024;
    bool has2 = eb < hi;
    // unconditional loads (clamped index) -> full MLP, no branches
    int p0 = packed[e];
    int p1 = packed[has2 ? eb : e];
    int s0 = p0 & 0xFFFFF, d0 = (p0 >> 20) & 127;
    int s1 = p1 & 0xFFFFF, d1 = (p1 >> 20) & 127;
    const uint4* q0 = (const uint4*)(ylb + (size_t)s0 * 8);
    const uint4* q1 = (const uint4*)(ylb + (size_t)s1 * 8);
    uint4 a0 = q0[0], a1 = q0[1];
    uint4 b0 = q1[0], b1 = q1[1];

    float* dp0 = &sagg[d0 * 17];
    ADD2(dp0, 0,  a0.x); ADD2(dp0, 2,  a0.y);
    ADD2(dp0, 4,  a0.z); ADD2(dp0, 6,  a0.w);
    ADD2(dp0, 8,  a1.x); ADD2(dp0, 10, a1.y);
    ADD2(dp0, 12, a1.z); ADD2(dp0, 14, a1.w);
    atomicAdd(&sdeg[d0], 1);
    if (has2) {
      float* dp1 = &sagg[d1 * 17];
      ADD2(dp1, 0,  b0.x); ADD2(dp1, 2,  b0.y);
      ADD2(dp1, 4,  b0.z); ADD2(dp1, 6,  b0.w);
      ADD2(dp1, 8,  b1.x); ADD2(dp1, 10, b1.y);
      ADD2(dp1, 12, b1.z); ADD2(dp1, 14, b1.w);
      atomicAdd(&sdeg[d1], 1);
    }
  }
  __syncthreads();

  int node0 = b * NODES_PER_BUCKET;
  for (int i = tid; i < NODES_PER_BUCKET * 16; i += 1024) {
    int node = node0 + (i >> 4);
    if (node < N) agg[(size_t)node0 * 16 + i] = sagg[(i >> 4) * 17 + (i & 15)];
  }
  if (tid < NODES_PER_BUCKET && node0 + tid < N) count[node0 + tid] = sdeg[tid];
}

// ---------------------------------------------------------------------------
// Finish: mean, +b_l+yr, relu, @W3+b3, log_softmax
// ---------------------------------------------------------------------------
__global__ __launch_bounds__(256) void finish_kernel(
    const float* __restrict__ agg, const int* __restrict__ count,
    const float* __restrict__ yr, const float* __restrict__ bl,
    const float* __restrict__ W3, const float* __restrict__ b3,
    float* __restrict__ out, int N) {
  __shared__ float sW3[16 * NCLS];
  __shared__ float sb3[NCLS];
  __shared__ float sbl[16];
  __shared__ float slog[256][NCLS + 1];

  int tid = threadIdx.x;
  for (int idx = tid; idx < 16 * NCLS; idx += 256) sW3[idx] = W3[idx];
  if (tid < NCLS) sb3[tid] = b3[tid];
  if (tid < 16) sbl[tid] = bl[tid];
  __syncthreads();

  int row0 = blockIdx.x * 256;
  int n = row0 + tid;
  if (n < N) {
    float inv = 1.0f / fmaxf((float)count[n], 1.0f);
    float h[16];
#pragma unroll
    for (int k = 0; k < 16; ++k)
      h[k] = fmaxf(agg[(size_t)n * 16 + k] * inv + sbl[k] + yr[(size_t)n * 16 + k], 0.0f);

    float lg[NCLS];
#pragma unroll
    for (int c = 0; c < NCLS; ++c) lg[c] = sb3[c];
#pragma unroll
    for (int k = 0; k < 16; ++k) {
      float hv = h[k];
#pragma unroll
      for (int c = 0; c < NCLS; ++c) lg[c] += hv * sW3[k * NCLS + c];
    }

    float m = lg[0];
#pragma unroll
    for (int c = 1; c < NCLS; ++c) m = fmaxf(m, lg[c]);
    float ssum = 0.f;
#pragma unroll
    for (int c = 0; c < NCLS; ++c) ssum += __expf(lg[c] - m);
    float lse = m + __logf(ssum);
#pragma unroll
    for (int c = 0; c < NCLS; ++c) slog[tid][c] = lg[c] - lse;
  }
  __syncthreads();

  int cnt = min(256, N - row0);
  int total = cnt * NCLS;
  for (int idx = tid; idx < total; idx += 256) {
    int r = idx / NCLS, c = idx - r * NCLS;
    out[(size_t)row0 * NCLS + idx] = slog[r][c];
  }
}

// ---------------------------------------------------------------------------
extern "C" void kernel_launch(void* const* d_in, const int* in_sizes, int n_in,
                              void* d_out, int out_size, void* d_ws, size_t ws_size,
                              hipStream_t stream) {
  const float* x   = (const float*)d_in[0];
  const int* eidx  = (const int*)d_in[1];
  const float* Wl  = (const float*)d_in[2];
  const float* bl  = (const float*)d_in[3];
  const float* Wr  = (const float*)d_in[4];
  const float* W3  = (const float*)d_in[5];
  const float* b3  = (const float*)d_in[6];
  float* out = (float*)d_out;

  int N = in_sizes[0] / D_FEAT;
  int E = in_sizes[1] / 2;
  const int* src = eidx;
  const int* dst = eidx + E;
  int B = (N + NODES_PER_BUCKET - 1) / NODES_PER_BUCKET;   // 782 for N=100000

  // workspace layout
  size_t n16 = (size_t)N * 16;
  float* yr  = (float*)d_ws;                 // N*16 f
  uint* ylb  = (uint*)(yr + n16);            // N*8 uint (bf16x2), 32B rows
  float* agg = (float*)(ylb + (size_t)N * 8);// N*16 f
  int* count  = (int*)(agg + n16);           // N
  int* bcount = count + N;                   // B
  int* boff   = bcount + B;                  // B+1
  int* gcur   = boff + B + 1;                // B
  int* packed = gcur + B;                    // E

  // 1) zero bucket counters (capture-safe async memset)
  hipMemsetAsync(bcount, 0, (size_t)B * sizeof(int), stream);

  // 2) bucket histogram
  int nbe = (E + EPB - 1) / EPB;
  bhist_kernel<<<nbe, 1024, 0, stream>>>(dst, bcount, E, B);

  // 3) scan -> boff, gcur
  bscan_kernel<<<1, 1024, 0, stream>>>(bcount, boff, gcur, B);

  // 4) place edges into buckets
  place_kernel<<<nbe, 1024, 0, stream>>>(src, dst, gcur, packed, E, B);

  // 5) projections (bf16 yl, f32 yr)
  lin_kernel<<<(N + 31) / 32, 256, 0, stream>>>(x, Wl, Wr, ylb, yr, N);

  // 6) bucket aggregate (LDS atomics only)
  baggr_kernel<<<B, 1024, 0, stream>>>(ylb, packed, boff, agg, count, N);

  // 7) finish
  finish_kernel<<<(N + 255) / 256, 256, 0, stream>>>(agg, count, yr, bl, W3, b3, out, N);
}

// Round 6
// 116.291 us; speedup vs baseline: 6.2196x; 3.6618x over previous
//
#include <hip/hip_runtime.h>
#include <hip/hip_bf16.h>

#define D_FEAT 128
#define HIDDEN 16
#define NCLS 40
#define NODES_PER_BUCKET 128      // bucket = dst >> 7
#define MAXB 1024                 // max buckets supported (N <= 131072)
#define EPB 16384                 // edges per block in hist/place
#define FXSCALE 262144.0f         // 2^18 fixed-point scale
#define FXINV   (1.0f / 262144.0f)

typedef unsigned int uint;

__device__ __forceinline__ uint f2bf(float x) {
  uint u = __float_as_uint(x);
  return (u + 0x7FFFu + ((u >> 16) & 1u)) >> 16;   // RNE
}

// ---------------------------------------------------------------------------
// Kernel: ylb = bf16pack(x @ W_l) ; yr = x @ W_r (f32)
// ---------------------------------------------------------------------------
__global__ __launch_bounds__(256) void lin_kernel(
    const float* __restrict__ x,
    const float* __restrict__ Wl, const float* __restrict__ Wr,
    uint* __restrict__ ylb, float* __restrict__ yr, int N) {
  __shared__ float sW[D_FEAT][8][4];
  __shared__ float sx[32][132];

  int tid = threadIdx.x;
  for (int idx = tid; idx < D_FEAT * 32; idx += 256) {
    int k = idx >> 5, o = idx & 31;
    float v = (o < 16) ? Wl[k * 16 + o] : Wr[k * 16 + (o - 16)];
    sW[k][o >> 2][o & 3] = v;
  }

  int row0 = blockIdx.x * 32;
  for (int q = tid; q < 32 * 32; q += 256) {
    int r = q >> 5, k4 = q & 31;
    int row = row0 + r;
    float4 v = make_float4(0.f, 0.f, 0.f, 0.f);
    if (row < N) v = *(const float4*)(x + (size_t)row * D_FEAT + k4 * 4);
    *(float4*)(&sx[r][k4 * 4]) = v;
  }
  __syncthreads();

  int r = tid >> 3, oq = tid & 7;
  int row = row0 + r;
  if (row < N) {
    float4 acc = make_float4(0.f, 0.f, 0.f, 0.f);
#pragma unroll
    for (int k = 0; k < D_FEAT; ++k) {
      float xv = sx[r][k];
      const float4 w = *(const float4*)(&sW[k][oq][0]);
      acc.x += xv * w.x; acc.y += xv * w.y;
      acc.z += xv * w.z; acc.w += xv * w.w;
    }
    if (oq < 4) {
      uint2 pk;
      pk.x = f2bf(acc.x) | (f2bf(acc.y) << 16);
      pk.y = f2bf(acc.z) | (f2bf(acc.w) << 16);
      *(uint2*)(ylb + (size_t)row * 8 + oq * 2) = pk;
    } else {
      *(float4*)(yr + (size_t)row * 16 + (oq - 4) * 4) = acc;
    }
  }
}

// ---------------------------------------------------------------------------
// Per-block LDS histogram of dst buckets -> global bcount
// ---------------------------------------------------------------------------
__global__ __launch_bounds__(1024) void bhist_kernel(
    const int* __restrict__ dst, int* __restrict__ bcount, int E, int B) {
  __shared__ int lh[MAXB];
  int tid = threadIdx.x;
  for (int i = tid; i < B; i += 1024) lh[i] = 0;
  __syncthreads();
  int base = blockIdx.x * EPB;
  int end = min(base + EPB, E);
  for (int e = base + tid; e < end; e += 1024)
    atomicAdd(&lh[dst[e] >> 7], 1);
  __syncthreads();
  for (int i = tid; i < B; i += 1024) {
    int c = lh[i];
    if (c) atomicAdd(&bcount[i], c);
  }
}

// ---------------------------------------------------------------------------
// Single-block scan over B (<=1024) buckets -> boff[B+1], gcur[B]
// ---------------------------------------------------------------------------
__global__ __launch_bounds__(1024) void bscan_kernel(
    const int* __restrict__ bcount, int* __restrict__ boff,
    int* __restrict__ gcur, int B) {
  __shared__ int s[1024];
  int tid = threadIdx.x;
  int v = (tid < B) ? bcount[tid] : 0;
  s[tid] = v;
  __syncthreads();
  for (int d = 1; d < 1024; d <<= 1) {
    int t = (tid >= d) ? s[tid - d] : 0;
    __syncthreads();
    if (tid >= d) s[tid] += t;
    __syncthreads();
  }
  if (tid < B) {
    int off = s[tid] - v;     // exclusive prefix
    boff[tid] = off;
    gcur[tid] = off;
  }
  if (tid == B - 1) boff[B] = s[tid];
}

// ---------------------------------------------------------------------------
// Place: block-level counting sort of edges into bucket-contiguous storage.
// packed = src | (local_dst << 20)
// ---------------------------------------------------------------------------
__global__ __launch_bounds__(1024) void place_kernel(
    const int* __restrict__ src, const int* __restrict__ dst,
    int* __restrict__ gcur, int* __restrict__ packed, int E, int B) {
  __shared__ int lh[MAXB];
  __shared__ int lbase[MAXB];
  int tid = threadIdx.x;
  for (int i = tid; i < B; i += 1024) lh[i] = 0;
  __syncthreads();
  int base = blockIdx.x * EPB;
  int end = min(base + EPB, E);
  for (int e = base + tid; e < end; e += 1024)
    atomicAdd(&lh[dst[e] >> 7], 1);
  __syncthreads();
  for (int i = tid; i < B; i += 1024) {
    int c = lh[i];
    lbase[i] = c ? atomicAdd(&gcur[i], c) : 0;
    lh[i] = 0;
  }
  __syncthreads();
  for (int e = base + tid; e < end; e += 1024) {
    int d = dst[e], s = src[e];
    int b = d >> 7;
    int p = atomicAdd(&lh[b], 1);
    packed[lbase[b] + p] = s | ((d & 127) << 20);
  }
}

// ---------------------------------------------------------------------------
// Bucket aggregate: lane-per-edge bf16 row gathers, INT32 fixed-point LDS
// atomics (native ds_add_u32 — f32 atomicAdd lowers to a CAS loop without
// -munsafe-fp-atomics, which was the ~340us wall in R1/R3/R4/R5).
// ---------------------------------------------------------------------------
#define ADDI2(ip, idx, u) do {                                              \
    float _lo = __uint_as_float((u) << 16);                                  \
    float _hi = __uint_as_float((u) & 0xFFFF0000u);                          \
    atomicAdd((ip) + (idx),     __float2int_rn(_lo * FXSCALE));              \
    atomicAdd((ip) + (idx) + 1, __float2int_rn(_hi * FXSCALE));              \
  } while (0)

__global__ __launch_bounds__(1024) void baggr_kernel(
    const uint* __restrict__ ylb, const int* __restrict__ packed,
    const int* __restrict__ boff, float* __restrict__ agg,
    int* __restrict__ count, int N) {
  __shared__ int sagg[NODES_PER_BUCKET * 17];   // stride 17: banks spread
  __shared__ int sdeg[NODES_PER_BUCKET];
  int tid = threadIdx.x;
  int b = blockIdx.x;
  for (int i = tid; i < NODES_PER_BUCKET * 17; i += 1024) sagg[i] = 0;
  if (tid < NODES_PER_BUCKET) sdeg[tid] = 0;
  __syncthreads();

  int lo = boff[b], hi = boff[b + 1];
  for (int e = lo + tid; e < hi; e += 2048) {
    int eb = e + 1024;
    bool has2 = eb < hi;
    int p0 = packed[e];
    int p1 = packed[has2 ? eb : e];
    int s0 = p0 & 0xFFFFF, d0 = (p0 >> 20) & 127;
    int s1 = p1 & 0xFFFFF, d1 = (p1 >> 20) & 127;
    const uint4* q0 = (const uint4*)(ylb + (size_t)s0 * 8);
    const uint4* q1 = (const uint4*)(ylb + (size_t)s1 * 8);
    uint4 a0 = q0[0], a1 = q0[1];
    uint4 b0 = q1[0], b1 = q1[1];

    int* ip0 = &sagg[d0 * 17];
    ADDI2(ip0, 0,  a0.x); ADDI2(ip0, 2,  a0.y);
    ADDI2(ip0, 4,  a0.z); ADDI2(ip0, 6,  a0.w);
    ADDI2(ip0, 8,  a1.x); ADDI2(ip0, 10, a1.y);
    ADDI2(ip0, 12, a1.z); ADDI2(ip0, 14, a1.w);
    atomicAdd(&sdeg[d0], 1);
    if (has2) {
      int* ip1 = &sagg[d1 * 17];
      ADDI2(ip1, 0,  b0.x); ADDI2(ip1, 2,  b0.y);
      ADDI2(ip1, 4,  b0.z); ADDI2(ip1, 6,  b0.w);
      ADDI2(ip1, 8,  b1.x); ADDI2(ip1, 10, b1.y);
      ADDI2(ip1, 12, b1.z); ADDI2(ip1, 14, b1.w);
      atomicAdd(&sdeg[d1], 1);
    }
  }
  __syncthreads();

  int node0 = b * NODES_PER_BUCKET;
  for (int i = tid; i < NODES_PER_BUCKET * 16; i += 1024) {
    int node = node0 + (i >> 4);
    if (node < N)
      agg[(size_t)node0 * 16 + i] =
          (float)sagg[(i >> 4) * 17 + (i & 15)] * FXINV;
  }
  if (tid < NODES_PER_BUCKET && node0 + tid < N) count[node0 + tid] = sdeg[tid];
}

// ---------------------------------------------------------------------------
// Finish: mean, +b_l+yr, relu, @W3+b3, log_softmax
// ---------------------------------------------------------------------------
__global__ __launch_bounds__(256) void finish_kernel(
    const float* __restrict__ agg, const int* __restrict__ count,
    const float* __restrict__ yr, const float* __restrict__ bl,
    const float* __restrict__ W3, const float* __restrict__ b3,
    float* __restrict__ out, int N) {
  __shared__ float sW3[16 * NCLS];
  __shared__ float sb3[NCLS];
  __shared__ float sbl[16];
  __shared__ float slog[256][NCLS + 1];

  int tid = threadIdx.x;
  for (int idx = tid; idx < 16 * NCLS; idx += 256) sW3[idx] = W3[idx];
  if (tid < NCLS) sb3[tid] = b3[tid];
  if (tid < 16) sbl[tid] = bl[tid];
  __syncthreads();

  int row0 = blockIdx.x * 256;
  int n = row0 + tid;
  if (n < N) {
    float inv = 1.0f / fmaxf((float)count[n], 1.0f);
    float h[16];
#pragma unroll
    for (int k = 0; k < 16; ++k)
      h[k] = fmaxf(agg[(size_t)n * 16 + k] * inv + sbl[k] + yr[(size_t)n * 16 + k], 0.0f);

    float lg[NCLS];
#pragma unroll
    for (int c = 0; c < NCLS; ++c) lg[c] = sb3[c];
#pragma unroll
    for (int k = 0; k < 16; ++k) {
      float hv = h[k];
#pragma unroll
      for (int c = 0; c < NCLS; ++c) lg[c] += hv * sW3[k * NCLS + c];
    }

    float m = lg[0];
#pragma unroll
    for (int c = 1; c < NCLS; ++c) m = fmaxf(m, lg[c]);
    float ssum = 0.f;
#pragma unroll
    for (int c = 0; c < NCLS; ++c) ssum += __expf(lg[c] - m);
    float lse = m + __logf(ssum);
#pragma unroll
    for (int c = 0; c < NCLS; ++c) slog[tid][c] = lg[c] - lse;
  }
  __syncthreads();

  int cnt = min(256, N - row0);
  int total = cnt * NCLS;
  for (int idx = tid; idx < total; idx += 256) {
    int r = idx / NCLS, c = idx - r * NCLS;
    out[(size_t)row0 * NCLS + idx] = slog[r][c];
  }
}

// ---------------------------------------------------------------------------
extern "C" void kernel_launch(void* const* d_in, const int* in_sizes, int n_in,
                              void* d_out, int out_size, void* d_ws, size_t ws_size,
                              hipStream_t stream) {
  const float* x   = (const float*)d_in[0];
  const int* eidx  = (const int*)d_in[1];
  const float* Wl  = (const float*)d_in[2];
  const float* bl  = (const float*)d_in[3];
  const float* Wr  = (const float*)d_in[4];
  const float* W3  = (const float*)d_in[5];
  const float* b3  = (const float*)d_in[6];
  float* out = (float*)d_out;

  int N = in_sizes[0] / D_FEAT;
  int E = in_sizes[1] / 2;
  const int* src = eidx;
  const int* dst = eidx + E;
  int B = (N + NODES_PER_BUCKET - 1) / NODES_PER_BUCKET;   // 782 for N=100000

  // workspace layout
  size_t n16 = (size_t)N * 16;
  float* yr  = (float*)d_ws;                 // N*16 f
  uint* ylb  = (uint*)(yr + n16);            // N*8 uint (bf16x2), 32B rows
  float* agg = (float*)(ylb + (size_t)N * 8);// N*16 f
  int* count  = (int*)(agg + n16);           // N
  int* bcount = count + N;                   // B
  int* boff   = bcount + B;                  // B+1
  int* gcur   = boff + B + 1;                // B
  int* packed = gcur + B;                    // E

  // 1) zero bucket counters (capture-safe async memset)
  hipMemsetAsync(bcount, 0, (size_t)B * sizeof(int), stream);

  // 2) bucket histogram
  int nbe = (E + EPB - 1) / EPB;
  bhist_kernel<<<nbe, 1024, 0, stream>>>(dst, bcount, E, B);

  // 3) scan -> boff, gcur
  bscan_kernel<<<1, 1024, 0, stream>>>(bcount, boff, gcur, B);

  // 4) place edges into buckets
  place_kernel<<<nbe, 1024, 0, stream>>>(src, dst, gcur, packed, E, B);

  // 5) projections (bf16 yl, f32 yr)
  lin_kernel<<<(N + 31) / 32, 256, 0, stream>>>(x, Wl, Wr, ylb, yr, N);

  // 6) bucket aggregate (native int LDS atomics)
  baggr_kernel<<<B, 1024, 0, stream>>>(ylb, packed, boff, agg, count, N);

  // 7) finish
  finish_kernel<<<(N + 255) / 256, 256, 0, stream>>>(agg, count, yr, bl, W3, b3, out, N);
}